// Round 1
// baseline (322.361 us; speedup 1.0000x reference)
//
#include <hip/hip_runtime.h>
#include <hip/hip_bf16.h>

// Row-wise cosine hinge loss:
//   j = (i + 1 + neg_idx[i]) % B
//   hinge_i = relu(1 - cos(t_i, o_i) + cos(t_j, o_i))
//   out = sum_i hinge_i / B
// One 256-thread block per row; 5 simultaneous reductions; atomicAdd of
// per-row contribution into the scalar output.

#define EPS 1e-6f

__device__ __forceinline__ float wave_reduce(float v) {
#pragma unroll
    for (int off = 32; off > 0; off >>= 1)
        v += __shfl_down(v, off, 64);
    return v;
}

__global__ __launch_bounds__(256) void hinge_cos_kernel(
    const float* __restrict__ outm,   // [B, D] "output" embeddings
    const float* __restrict__ tgt,    // [B, D] "target" embeddings
    const int*   __restrict__ negidx, // [B]
    float* __restrict__ res,          // [1] scalar result (pre-zeroed)
    int B, int D, float invB) {

    const int i = blockIdx.x;
    int j = i + 1 + negidx[i];        // neg_idx in [0, B-1) => j in [1, 2B-1)
    if (j >= B) j -= B;

    const float4* o4 = (const float4*)(outm + (size_t)i * D);
    const float4* t4 = (const float4*)(tgt  + (size_t)i * D);
    const float4* n4 = (const float4*)(tgt  + (size_t)j * D);

    float d_to = 0.f, d_no = 0.f, oo = 0.f, tt = 0.f, nn = 0.f;
    const int nvec = D >> 2;
    for (int c = threadIdx.x; c < nvec; c += blockDim.x) {
        float4 o = o4[c];
        float4 t = t4[c];
        float4 n = n4[c];
        d_to += o.x * t.x + o.y * t.y + o.z * t.z + o.w * t.w;
        d_no += o.x * n.x + o.y * n.y + o.z * n.z + o.w * n.w;
        oo   += o.x * o.x + o.y * o.y + o.z * o.z + o.w * o.w;
        tt   += t.x * t.x + t.y * t.y + t.z * t.z + t.w * t.w;
        nn   += n.x * n.x + n.y * n.y + n.z * n.z + n.w * n.w;
    }

    // wave-level reduce (wave64)
    d_to = wave_reduce(d_to);
    d_no = wave_reduce(d_no);
    oo   = wave_reduce(oo);
    tt   = wave_reduce(tt);
    nn   = wave_reduce(nn);

    // cross-wave reduce via LDS (blockDim=256 -> 4 waves)
    __shared__ float red[4][5];
    const int wave = threadIdx.x >> 6;
    const int lane = threadIdx.x & 63;
    if (lane == 0) {
        red[wave][0] = d_to;
        red[wave][1] = d_no;
        red[wave][2] = oo;
        red[wave][3] = tt;
        red[wave][4] = nn;
    }
    __syncthreads();

    if (threadIdx.x == 0) {
        float s0 = 0.f, s1 = 0.f, s2 = 0.f, s3 = 0.f, s4 = 0.f;
#pragma unroll
        for (int w = 0; w < 4; ++w) {
            s0 += red[w][0];
            s1 += red[w][1];
            s2 += red[w][2];
            s3 += red[w][3];
            s4 += red[w][4];
        }
        float no = sqrtf(s2);                 // ||o||
        float den1 = fmaxf(sqrtf(s3) * no, EPS);
        float den2 = fmaxf(sqrtf(s4) * no, EPS);
        float hinge = 1.f - s0 / den1 + s1 / den2;
        if (hinge > 0.f)
            atomicAdd(res, hinge * invB);
    }
}

extern "C" void kernel_launch(void* const* d_in, const int* in_sizes, int n_in,
                              void* d_out, int out_size, void* d_ws, size_t ws_size,
                              hipStream_t stream) {
    const float* outm   = (const float*)d_in[0];
    const float* tgt    = (const float*)d_in[1];
    const int*   negidx = (const int*)d_in[2];
    float* res = (float*)d_out;

    const int B = in_sizes[2];
    const int D = in_sizes[0] / B;

    // d_out is re-poisoned to 0xAA before every launch; zero it (capture-safe).
    hipMemsetAsync(res, 0, sizeof(float), stream);

    hinge_cos_kernel<<<B, 256, 0, stream>>>(outm, tgt, negidx, res, B, D,
                                            1.0f / (float)B);
}

// Round 2
// 154.299 us; speedup vs baseline: 2.0892x; 2.0892x over previous
//
#include <hip/hip_runtime.h>
#include <hip/hip_bf16.h>

// Row-wise cosine hinge loss, wave-per-row persistent version.
//   j = (i + 1 + neg_idx[i]) % B
//   hinge_i = relu(1 - cos(t_i, o_i) + cos(t_j, o_i))
//   out = sum_i hinge_i / B
//
// One 64-lane wave per row (D=1024 -> 4 float4 chunks per lane per array ->
// 12 independent loads in flight). Grid-stride over rows; per-wave hinge
// accumulator; one atomicAdd per block.

#define EPS 1e-6f

__device__ __forceinline__ float wave_reduce_xor(float v) {
#pragma unroll
    for (int off = 32; off > 0; off >>= 1)
        v += __shfl_xor(v, off, 64);
    return v;
}

__global__ __launch_bounds__(256) void hinge_cos_kernel(
    const float* __restrict__ outm,   // [B, D]
    const float* __restrict__ tgt,    // [B, D]
    const int*   __restrict__ negidx, // [B]
    float* __restrict__ res,          // [1] scalar (pre-zeroed)
    int B, int D, float invB) {

    const int lane  = threadIdx.x & 63;
    const int wave  = threadIdx.x >> 6;
    const int wpb   = blockDim.x >> 6;           // waves per block (4)
    const int gwave = blockIdx.x * wpb + wave;   // global wave id
    const int nwav  = gridDim.x * wpb;           // total waves
    const int nvec  = D >> 2;                    // float4 per row (256)
    const int CH    = 4;                         // chunks per lane (256/64)

    float acc = 0.f;                             // per-wave hinge sum (lane 0)

    for (int i = gwave; i < B; i += nwav) {
        int j = i + 1 + negidx[i];
        if (j >= B) j -= B;

        const float4* o4 = (const float4*)(outm + (size_t)i * D);
        const float4* t4 = (const float4*)(tgt  + (size_t)i * D);
        const float4* n4 = (const float4*)(tgt  + (size_t)j * D);

        // Issue all 12 loads before any use: maximize MLP.
        float4 o[CH], t[CH], n[CH];
#pragma unroll
        for (int k = 0; k < CH; ++k) o[k] = o4[lane + 64 * k];
#pragma unroll
        for (int k = 0; k < CH; ++k) t[k] = t4[lane + 64 * k];
#pragma unroll
        for (int k = 0; k < CH; ++k) n[k] = n4[lane + 64 * k];

        float d_to = 0.f, d_no = 0.f, oo = 0.f, tt = 0.f, nn = 0.f;
#pragma unroll
        for (int k = 0; k < CH; ++k) {
            d_to += o[k].x * t[k].x + o[k].y * t[k].y + o[k].z * t[k].z + o[k].w * t[k].w;
            d_no += o[k].x * n[k].x + o[k].y * n[k].y + o[k].z * n[k].z + o[k].w * n[k].w;
            oo   += o[k].x * o[k].x + o[k].y * o[k].y + o[k].z * o[k].z + o[k].w * o[k].w;
            tt   += t[k].x * t[k].x + t[k].y * t[k].y + t[k].z * t[k].z + t[k].w * t[k].w;
            nn   += n[k].x * n[k].x + n[k].y * n[k].y + n[k].z * n[k].z + n[k].w * n[k].w;
        }

        d_to = wave_reduce_xor(d_to);
        d_no = wave_reduce_xor(d_no);
        oo   = wave_reduce_xor(oo);
        tt   = wave_reduce_xor(tt);
        nn   = wave_reduce_xor(nn);

        if (lane == 0) {
            float no   = sqrtf(oo);
            float den1 = fmaxf(sqrtf(tt) * no, EPS);
            float den2 = fmaxf(sqrtf(nn) * no, EPS);
            float hinge = 1.f - d_to / den1 + d_no / den2;
            if (hinge > 0.f) acc += hinge;
        }
    }

    // Block-level: lane 0 of each wave holds its partial; one atomic per block.
    __shared__ float red[4];
    if (lane == 0) red[wave] = acc;
    __syncthreads();
    if (threadIdx.x == 0) {
        float s = 0.f;
#pragma unroll
        for (int w = 0; w < 4; ++w) s += red[w];
        atomicAdd(res, s * invB);
    }
}

extern "C" void kernel_launch(void* const* d_in, const int* in_sizes, int n_in,
                              void* d_out, int out_size, void* d_ws, size_t ws_size,
                              hipStream_t stream) {
    const float* outm   = (const float*)d_in[0];
    const float* tgt    = (const float*)d_in[1];
    const int*   negidx = (const int*)d_in[2];
    float* res = (float*)d_out;

    const int B = in_sizes[2];
    const int D = in_sizes[0] / B;

    hipMemsetAsync(res, 0, sizeof(float), stream);

    // 2048 blocks x 256 thr = 8192 waves = full residency on 256 CUs;
    // each wave grid-strides over 2 rows.
    hinge_cos_kernel<<<2048, 256, 0, stream>>>(outm, tgt, negidx, res, B, D,
                                               1.0f / (float)B);
}